// Round 1
// baseline (3507.574 us; speedup 1.0000x reference)
//
#include <hip/hip_runtime.h>
#include <hip/hip_bf16.h>

#define BATCH 64
#define SEQ 2048
#define IN_DIM 256
#define UNITS 256

typedef _Float16 half2_t __attribute__((ext_vector_type(2)));

__device__ __forceinline__ float fdot2(half2_t a, half2_t b, float c) {
#if __has_builtin(__builtin_amdgcn_fdot2)
    return __builtin_amdgcn_fdot2(a, b, c, false);
#else
    return c + (float)a[0] * (float)b[0] + (float)a[1] * (float)b[1];
#endif
}

// ---------------------------------------------------------------------------
// Prep: transpose U_f, U_s (K x U, fp32) -> Ut (U x K, f16) so each recurrence
// thread's 64-long K-slice of one column is contiguous (8 x dwordx4 loads).
// ---------------------------------------------------------------------------
__global__ void prep_u(const float* __restrict__ Uf, const float* __restrict__ Us,
                       _Float16* __restrict__ Utf, _Float16* __restrict__ Uts) {
    int idx = blockIdx.x * 256 + threadIdx.x;   // 65536 total
    int k = idx >> 8;
    int u = idx & 255;
    Utf[u * 256 + k] = (_Float16)Uf[idx];
    Uts[u * 256 + k] = (_Float16)Us[idx];
}

// ---------------------------------------------------------------------------
// Projection GEMM: C[r][n] = X[r][:] @ W[:][n] + bias,  r in [0,131072)
// 64x64 output tile per workgroup, K chunked by 64.  blockIdx.y 0..3 -> W_f
// tiles (fp32 into d_out), 4..7 -> W_s tiles (f16 into ws).
// ---------------------------------------------------------------------------
__global__ __launch_bounds__(256) void proj_kernel(
    const float* __restrict__ X,
    const float* __restrict__ Wf, const float* __restrict__ bf,
    const float* __restrict__ Wsm, const float* __restrict__ bs,
    float* __restrict__ xf_out, _Float16* __restrict__ xs_out)
{
    __shared__ float Xs[64][65];    // 64 rows x 64 k, pad 65 -> conflict-free
    __shared__ float Wsh[64][68];   // 64 k x 64 n, pad 68 keeps 16B alignment

    const int tid = threadIdx.x;
    const int rt = blockIdx.x;
    const int ct = blockIdx.y;
    const int r0 = rt * 64;
    const bool is_f = ct < 4;
    const int c0 = (ct & 3) * 64;
    const float* W = is_f ? Wf : Wsm;
    const float* bias = is_f ? bf : bs;
    const int tx = tid & 15;   // row quad
    const int ty = tid >> 4;   // col quad

    float acc[4][4];
#pragma unroll
    for (int i = 0; i < 4; ++i)
#pragma unroll
        for (int j = 0; j < 4; ++j) acc[i][j] = 0.f;

    for (int kc = 0; kc < IN_DIM; kc += 64) {
        __syncthreads();
        // load X chunk: 64 rows x 64 k = 1024 float4
#pragma unroll
        for (int i = 0; i < 4; ++i) {
            int f = tid + i * 256;
            int row = f >> 4;          // 16 float4 per row
            int kq = f & 15;
            float4 v = *(const float4*)(X + (size_t)(r0 + row) * IN_DIM + kc + kq * 4);
            Xs[row][kq * 4 + 0] = v.x;
            Xs[row][kq * 4 + 1] = v.y;
            Xs[row][kq * 4 + 2] = v.z;
            Xs[row][kq * 4 + 3] = v.w;
        }
        // load W chunk: 64 k x 64 n
#pragma unroll
        for (int i = 0; i < 4; ++i) {
            int f = tid + i * 256;
            int kk = f >> 4;
            int n4 = f & 15;
            float4 v = *(const float4*)(W + (size_t)(kc + kk) * UNITS + c0 + n4 * 4);
            *(float4*)&Wsh[kk][n4 * 4] = v;
        }
        __syncthreads();
#pragma unroll 8
        for (int kk = 0; kk < 64; ++kk) {
            float a0 = Xs[tx * 4 + 0][kk];
            float a1 = Xs[tx * 4 + 1][kk];
            float a2 = Xs[tx * 4 + 2][kk];
            float a3 = Xs[tx * 4 + 3][kk];
            float4 bv = *(const float4*)&Wsh[kk][ty * 4];
            acc[0][0] += a0 * bv.x; acc[0][1] += a0 * bv.y; acc[0][2] += a0 * bv.z; acc[0][3] += a0 * bv.w;
            acc[1][0] += a1 * bv.x; acc[1][1] += a1 * bv.y; acc[1][2] += a1 * bv.z; acc[1][3] += a1 * bv.w;
            acc[2][0] += a2 * bv.x; acc[2][1] += a2 * bv.y; acc[2][2] += a2 * bv.z; acc[2][3] += a2 * bv.w;
            acc[3][0] += a3 * bv.x; acc[3][1] += a3 * bv.y; acc[3][2] += a3 * bv.z; acc[3][3] += a3 * bv.w;
        }
    }

#pragma unroll
    for (int i = 0; i < 4; ++i) {
        int r = r0 + tx * 4 + i;
        int n0 = c0 + ty * 4;
        if (is_f) {
            float4 v;
            v.x = acc[i][0] + bias[n0 + 0];
            v.y = acc[i][1] + bias[n0 + 1];
            v.z = acc[i][2] + bias[n0 + 2];
            v.w = acc[i][3] + bias[n0 + 3];
            *(float4*)(xf_out + (size_t)r * UNITS + n0) = v;
        } else {
#pragma unroll
            for (int j = 0; j < 4; ++j)
                xs_out[(size_t)r * UNITS + n0 + j] = (_Float16)(acc[i][j] + bias[n0 + j]);
        }
    }
}

// ---------------------------------------------------------------------------
// Recurrence: one workgroup (1024 thr) per batch element.  Thread (u, q)
// holds U_f[64q..64q+63][u] and U_s[...][u] as f16 pairs in registers.
// h lives in LDS (fp32 + packed f16).  Per step:
//   a) partials of h @ U_f     b) f = sigmoid(xf + .), g = f*h
//   c) partials of g @ U_s     d) s = tanh(xs + .), h = (1-f)h + f s, store
// ---------------------------------------------------------------------------
__global__ __launch_bounds__(1024) void recur_kernel(
    float* xf_out,                       // aliases d_out: xf in, h out (no restrict!)
    const _Float16* __restrict__ xs16,   // [B][T][U]
    const _Float16* __restrict__ Utf,    // [U][K] f16
    const _Float16* __restrict__ Uts)    // [U][K] f16
{
    __shared__ float part[4][256];
    __shared__ float hbuf[256];
    __shared__ float fbuf[256];
    __shared__ __align__(16) _Float16 h2[256];
    __shared__ __align__(16) _Float16 g2[256];

    const int tid = threadIdx.x;
    const int u = tid & 255;
    const int q = tid >> 8;
    const int b = blockIdx.x;

    union F4H { float4 f4; half2_t h[4]; };

    // register-resident weight slices: 32 f16-pairs per matrix
    half2_t uf[32], us[32];
    {
        const float4* pf = (const float4*)(Utf + ((size_t)u * 256 + q * 64));
        const float4* ps = (const float4*)(Uts + ((size_t)u * 256 + q * 64));
#pragma unroll
        for (int j = 0; j < 8; ++j) {
            F4H a; a.f4 = pf[j];
            F4H c; c.f4 = ps[j];
#pragma unroll
            for (int m = 0; m < 4; ++m) {
                uf[4 * j + m] = a.h[m];
                us[4 * j + m] = c.h[m];
            }
        }
    }

    if (tid < 256) {
        hbuf[tid] = 0.f;
        h2[tid] = (_Float16)0.f;
    }
    __syncthreads();

    const size_t base = (size_t)b * SEQ * UNITS;

    for (int t = 0; t < SEQ; ++t) {
        float xfv = 0.f, xsv = 0.f;
        if (tid < 256) {
            xfv = xf_out[base + (size_t)t * UNITS + tid];
            xsv = (float)xs16[base + (size_t)t * UNITS + tid];
        }

        // ---- phase a: partials of h @ U_f
        {
            const float4* hv4 = (const float4*)h2;
            float a0 = 0.f, a1 = 0.f, a2 = 0.f, a3 = 0.f;
#pragma unroll
            for (int j = 0; j < 8; ++j) {
                F4H hh; hh.f4 = hv4[8 * q + j];
                a0 = fdot2(uf[4 * j + 0], hh.h[0], a0);
                a1 = fdot2(uf[4 * j + 1], hh.h[1], a1);
                a2 = fdot2(uf[4 * j + 2], hh.h[2], a2);
                a3 = fdot2(uf[4 * j + 3], hh.h[3], a3);
            }
            part[q][u] = (a0 + a1) + (a2 + a3);
        }
        __syncthreads();

        // ---- phase b: forget gate
        if (tid < 256) {
            float sum = (part[0][tid] + part[1][tid]) + (part[2][tid] + part[3][tid]);
            float f = 1.f / (1.f + __expf(-(xfv + sum)));
            fbuf[tid] = f;
            g2[tid] = (_Float16)(f * hbuf[tid]);
        }
        __syncthreads();

        // ---- phase c: partials of (f*h) @ U_s
        {
            const float4* gv4 = (const float4*)g2;
            float a0 = 0.f, a1 = 0.f, a2 = 0.f, a3 = 0.f;
#pragma unroll
            for (int j = 0; j < 8; ++j) {
                F4H hh; hh.f4 = gv4[8 * q + j];
                a0 = fdot2(us[4 * j + 0], hh.h[0], a0);
                a1 = fdot2(us[4 * j + 1], hh.h[1], a1);
                a2 = fdot2(us[4 * j + 2], hh.h[2], a2);
                a3 = fdot2(us[4 * j + 3], hh.h[3], a3);
            }
            part[q][u] = (a0 + a1) + (a2 + a3);
        }
        __syncthreads();

        // ---- phase d: candidate + state update + output
        if (tid < 256) {
            float sum = (part[0][tid] + part[1][tid]) + (part[2][tid] + part[3][tid]);
            float z = xsv + sum;
            z = fminf(fmaxf(z, -15.f), 15.f);
            float e = __expf(2.f * z);
            float s = (e - 1.f) / (e + 1.f);
            float f = fbuf[tid];
            float hv = hbuf[tid];
            float hn = (1.f - f) * hv + f * s;
            hbuf[tid] = hn;
            h2[tid] = (_Float16)hn;
            xf_out[base + (size_t)t * UNITS + tid] = hn;
        }
        __syncthreads();
    }
}

extern "C" void kernel_launch(void* const* d_in, const int* in_sizes, int n_in,
                              void* d_out, int out_size, void* d_ws, size_t ws_size,
                              hipStream_t stream) {
    (void)in_sizes; (void)n_in; (void)out_size; (void)ws_size;

    const float* X   = (const float*)d_in[0];
    const float* Wf  = (const float*)d_in[1];
    const float* Uf  = (const float*)d_in[2];
    const float* bf  = (const float*)d_in[3];
    const float* Wsm = (const float*)d_in[4];
    const float* Us  = (const float*)d_in[5];
    const float* bs  = (const float*)d_in[6];
    float* out = (float*)d_out;

    // ws layout: xs16 (64 MB) | Utf (128 KB) | Uts (128 KB)
    _Float16* xs16 = (_Float16*)d_ws;
    _Float16* Utf  = xs16 + (size_t)BATCH * SEQ * UNITS;
    _Float16* Uts  = Utf + 256 * 256;

    prep_u<<<256, 256, 0, stream>>>(Uf, Us, Utf, Uts);
    proj_kernel<<<dim3(BATCH * SEQ / 64, 8), 256, 0, stream>>>(X, Wf, bf, Wsm, bs, out, xs16);
    recur_kernel<<<BATCH, 1024, 0, stream>>>(out, xs16, Utf, Uts);
}